// Round 7
// baseline (2612.496 us; speedup 1.0000x reference)
//
#include <hip/hip_runtime.h>
#include <cstddef>

#define MDIM 512
#define DDIM 1024
#define BDIM 4096
#define NLAYERS 16

__device__ __forceinline__ float softf(float v, float t) {
  // relu(v-t) - relu(-v-t) == copysign(max(|v|-t,0), v)
  return copysignf(fmaxf(fabsf(v) - t, 0.0f), v);
}

// ---------------------------------------------------------------------------
// C = P(rows x K, row-major) @ B(K x 4096, row-major), fused epilogue.
// Bit-exact accumulation: per output element one fmaf chain, k ascending
// (chunks of 8 ascending, j ascending within chunk) — identical chain to the
// round-5 kernel that passed (absmax 0.2304688).
// LDS-free / barrier-free: each wave owns TM rows x 256 cols (lane -> 4
// contiguous cols). B double-buffered in registers (8 k-values per chunk),
// A read via wave-uniform addresses (scalar/broadcast loads).
// MODE 0: layer-0 A-kernel; MODE 1: scan A-kernel; MODE 2: B-kernel (soft-Z)
// ---------------------------------------------------------------------------
template <int MODE, int K, int TM>
__global__ __launch_bounds__(256) void gemm_rr(
    const float* __restrict__ P, const float* __restrict__ Bm,
    const float* __restrict__ xg, const float* __restrict__ Ep,
    const float* __restrict__ Lp, const float* __restrict__ Zp,
    const float* __restrict__ beta1, const float* __restrict__ beta2,
    const float* __restrict__ beta3, const float* __restrict__ ss2,
    const float* __restrict__ apar, const float* __restrict__ apar1, int k,
    float* __restrict__ O0, float* __restrict__ O1, float* __restrict__ O2) {
  const int lane = threadIdx.x & 63;
  // wave id forced wave-uniform so all A addressing is SGPR-computable
  const int w = __builtin_amdgcn_readfirstlane((int)(threadIdx.x >> 6));
  const int r0 = blockIdx.x * (4 * TM) + w * TM;
  const int c0 = blockIdx.y * 256 + lane * 4;

  const float* pA = P + (size_t)r0 * K;
  const float* pB = Bm + c0;

  float acc[TM][4];
#pragma unroll
  for (int r = 0; r < TM; ++r)
#pragma unroll
    for (int c = 0; c < 4; ++c) acc[r][c] = 0.0f;

  float4 b0[8], b1[8];

  auto loadB = [&](float4 (&bb)[8], int kc) {
    const float* base = pB + (size_t)kc * 8 * BDIM;
#pragma unroll
    for (int j = 0; j < 8; ++j)
      bb[j] = *reinterpret_cast<const float4*>(base + (size_t)j * BDIM);
  };

  auto compute = [&](const float4 (&bb)[8], int kc) {
#pragma unroll
    for (int r = 0; r < TM; ++r) {
      const float* aR = pA + (size_t)r * K + kc * 8;
      float a[8];
#pragma unroll
      for (int j = 0; j < 8; ++j) a[j] = aR[j];  // wave-uniform loads
#pragma unroll
      for (int j = 0; j < 8; ++j) {
        acc[r][0] = fmaf(a[j], bb[j].x, acc[r][0]);
        acc[r][1] = fmaf(a[j], bb[j].y, acc[r][1]);
        acc[r][2] = fmaf(a[j], bb[j].z, acc[r][2]);
        acc[r][3] = fmaf(a[j], bb[j].w, acc[r][3]);
      }
    }
  };

  constexpr int NC = K / 8;  // 128 or 64, always even and >= 4
  loadB(b0, 0);
#pragma unroll 1
  for (int kc = 0; kc + 2 < NC; kc += 2) {
    loadB(b1, kc + 1);
    compute(b0, kc);
    loadB(b0, kc + 2);
    compute(b1, kc + 1);
  }
  loadB(b1, NC - 1);
  compute(b0, NC - 2);
  compute(b1, NC - 1);

  // ---- epilogue (expressions identical to round-5 kernel) ----
  const float b1v = (MODE == 2) ? 0.f : beta1[k];
  float b2v = 0.f, b3v = 0.f, s2v = 0.f, a1v = 0.f, ap = 0.f;
  if (MODE == 1) {
    b2v = beta2[k - 1];
    b3v = beta3[k - 1];
    s2v = ss2[k - 1];
    a1v = apar1[k - 1];
  }
  if (MODE == 2) ap = apar[k];

#pragma unroll
  for (int r = 0; r < TM; ++r) {
    const size_t off = (size_t)(r0 + r) * BDIM + c0;
    if (MODE == 2) {
      const float4 z4 = *reinterpret_cast<const float4*>(&Zp[off]);
      const float z[4] = {z4.x, z4.y, z4.z, z4.w};
      float o[4];
#pragma unroll
      for (int j = 0; j < 4; ++j) o[j] = softf(z[j] - acc[r][j], ap);
      *reinterpret_cast<float4*>(&O0[off]) =
          *reinterpret_cast<const float4*>(&o[0]);
    } else {
      float ev[4], lv[4], xv[4];
      *reinterpret_cast<float4*>(&ev[0]) =
          *reinterpret_cast<const float4*>(&Ep[off]);
      *reinterpret_cast<float4*>(&lv[0]) =
          *reinterpret_cast<const float4*>(&Lp[off]);
      *reinterpret_cast<float4*>(&xv[0]) =
          *reinterpret_cast<const float4*>(&xg[off]);
      float vo[4], eo[4], lo_[4];
#pragma unroll
      for (int j = 0; j < 4; ++j) {
        const float az = acc[r][j];
        if (MODE == 0) {
          const float t0 = az + ev[j] - xv[j];
          vo[j] = fmaf(b1v, t0, lv[j]);
          eo[j] = ev[j];
          lo_[j] = lv[j];
        } else {
          const float vv = fmaf(b2v, az + ev[j] - xv[j], lv[j]);
          const float en = softf(ev[j] - s2v * vv, a1v);
          const float tn_ = az + en - xv[j];
          const float ln = fmaf(b3v, tn_, lv[j]);
          eo[j] = en;
          lo_[j] = ln;
          vo[j] = fmaf(b1v, tn_, ln);
        }
      }
      *reinterpret_cast<float4*>(&O0[off]) =
          *reinterpret_cast<const float4*>(&vo[0]);
      *reinterpret_cast<float4*>(&O1[off]) =
          *reinterpret_cast<const float4*>(&eo[0]);
      *reinterpret_cast<float4*>(&O2[off]) =
          *reinterpret_cast<const float4*>(&lo_[0]);
    }
  }
}

extern "C" void kernel_launch(void* const* d_in, const int* in_sizes, int n_in,
                              void* d_out, int out_size, void* d_ws,
                              size_t ws_size, hipStream_t stream) {
  (void)in_sizes;
  (void)n_in;
  (void)out_size;
  (void)ws_size;
  const float* x = (const float*)d_in[0];
  const float* A = (const float*)d_in[1];
  const float* W = (const float*)d_in[2];
  const float* Z0 = (const float*)d_in[3];
  const float* E0 = (const float*)d_in[4];
  const float* L0 = (const float*)d_in[5];
  const float* beta1 = (const float*)d_in[6];
  const float* beta2 = (const float*)d_in[7];
  const float* beta3 = (const float*)d_in[8];
  const float* ss2 = (const float*)d_in[9];
  const float* apar = (const float*)d_in[10];
  const float* apar1 = (const float*)d_in[11];

  constexpr size_t DB = (size_t)DDIM * BDIM;
  constexpr size_t MB = (size_t)MDIM * BDIM;
  float* Zall = (float*)d_out;
  float* Eall = Zall + (size_t)NLAYERS * DB;
  float* Lall = Eall + (size_t)NLAYERS * MB;
  float* Var = (float*)d_ws;  // MDIM*BDIM floats = 8 MiB

  const dim3 blk(256);
  // A-GEMM: TM=4 -> block covers 16 rows: grid (512/16, 4096/256) = (32,16)
  const dim3 gA(MDIM / 16, BDIM / 256);
  // B-GEMM: TM=8 -> block covers 32 rows: grid (1024/32, 4096/256) = (32,16)
  const dim3 gB(DDIM / 32, BDIM / 256);

  // layer 0
  gemm_rr<0, DDIM, 4><<<gA, blk, 0, stream>>>(
      A, Z0, x, E0, L0, nullptr, beta1, beta2, beta3, ss2, apar, apar1, 0, Var,
      Eall, Lall);
  gemm_rr<2, MDIM, 8><<<gB, blk, 0, stream>>>(
      W, Var, nullptr, nullptr, nullptr, Z0, beta1, beta2, beta3, ss2, apar,
      apar1, 0, Zall, nullptr, nullptr);
  // layers 1..15
  for (int k = 1; k < NLAYERS; ++k) {
    const float* Zp = Zall + (size_t)(k - 1) * DB;
    gemm_rr<1, DDIM, 4><<<gA, blk, 0, stream>>>(
        A, Zp, x, Eall + (size_t)(k - 1) * MB, Lall + (size_t)(k - 1) * MB,
        nullptr, beta1, beta2, beta3, ss2, apar, apar1, k, Var,
        Eall + (size_t)k * MB, Lall + (size_t)k * MB);
    gemm_rr<2, MDIM, 8><<<gB, blk, 0, stream>>>(
        W + (size_t)k * DDIM * MDIM, Var, nullptr, nullptr, nullptr, Zp, beta1,
        beta2, beta3, ss2, apar, apar1, k, Zall + (size_t)k * DB, nullptr,
        nullptr);
  }
}

// Round 8
// 2444.767 us; speedup vs baseline: 1.0686x; 1.0686x over previous
//
#include <hip/hip_runtime.h>
#include <cstddef>

#define MDIM 512
#define DDIM 1024
#define BDIM 4096
#define NLAYERS 16

constexpr int BK = 16;

__device__ __forceinline__ float softf(float v, float t) {
  // relu(v-t) - relu(-v-t) == copysign(max(|v|-t,0), v)
  return copysignf(fmaxf(fabsf(v) - t, 0.0f), v);
}

// ---------------------------------------------------------------------------
// C = P(rows x K, row-major) @ B(K x 4096, row-major), fused epilogue.
// Bit-exact accumulation: per output element one fmaf chain, k ascending
// (BK=16 chunks ascending, kk ascending within chunk) — identical chain to
// rounds 1/5 (absmax 0.2304688).
// Tile 32x128, 4 waves; wave = 8 rows x 128 cols, lane -> 2 cols.
//  - B from LDS: float2/lane/kk = 0.5 B/fma  (no LDS BW cap)
//  - A from LDS via wave-uniform broadcast reads (free)
// MODE 0: layer-0 A-kernel; MODE 1: scan A-kernel; MODE 2: B-kernel (soft-Z)
// ---------------------------------------------------------------------------
template <int MODE, int K>
__global__ __launch_bounds__(256) void gemm_bc(
    const float* __restrict__ P, const float* __restrict__ Bm,
    const float* __restrict__ xg, const float* __restrict__ Ep,
    const float* __restrict__ Lp, const float* __restrict__ Zp,
    const float* __restrict__ beta1, const float* __restrict__ beta2,
    const float* __restrict__ beta3, const float* __restrict__ ss2,
    const float* __restrict__ apar, const float* __restrict__ apar1, int k,
    float* __restrict__ O0, float* __restrict__ O1, float* __restrict__ O2) {
  __shared__ __align__(16) float As[2][BK][32];
  __shared__ __align__(16) float Bs[2][BK][128];

  const int tid = threadIdx.x;
  const int lane = tid & 63;
  const int w = __builtin_amdgcn_readfirstlane((int)(tid >> 6));
  const int m0 = blockIdx.x * 32, n0 = blockIdx.y * 128;
  const int r0 = m0 + w * 8;          // wave's first row (wave-uniform)
  const int c0 = n0 + lane * 2;       // thread's first col

  float acc[8][2];
#pragma unroll
  for (int r = 0; r < 8; ++r) {
    acc[r][0] = 0.0f;
    acc[r][1] = 0.0f;
  }

  // A staging map: thread -> (row ar, k-pair akc)
  const int ar = tid >> 3, akc = (tid & 7) * 2;
  const float* gA = P + (size_t)(m0 + ar) * K + akc;
  // B staging map: thread -> (row br, col-chunk bc of 8)
  const int br = tid >> 4, bc = (tid & 15) * 8;
  const float* gB = Bm + (size_t)br * BDIM + n0 + bc;

  float2 rA;
  float4 rB0, rB1;
  auto gload = [&](int k0) {
    rA = *reinterpret_cast<const float2*>(gA + (size_t)k0);
    rB0 = *reinterpret_cast<const float4*>(gB + (size_t)k0 * BDIM);
    rB1 = *reinterpret_cast<const float4*>(gB + (size_t)k0 * BDIM + 4);
  };
  auto stagewr = [&](int bb) {
    As[bb][akc][ar] = rA.x;
    As[bb][akc + 1][ar] = rA.y;
    *reinterpret_cast<float4*>(&Bs[bb][br][bc]) = rB0;
    *reinterpret_cast<float4*>(&Bs[bb][br][bc + 4]) = rB1;
  };
  auto comp = [&](int bb) {
#pragma unroll
    for (int kk = 0; kk < BK; ++kk) {
      // wave-uniform broadcast reads of the 8 A values
      const float4 a0 = *reinterpret_cast<const float4*>(&As[bb][kk][w * 8]);
      const float4 a1 =
          *reinterpret_cast<const float4*>(&As[bb][kk][w * 8 + 4]);
      const float a[8] = {a0.x, a0.y, a0.z, a0.w, a1.x, a1.y, a1.z, a1.w};
      const float2 b2 = *reinterpret_cast<const float2*>(&Bs[bb][kk][lane * 2]);
#pragma unroll
      for (int r = 0; r < 8; ++r) {
        acc[r][0] = fmaf(a[r], b2.x, acc[r][0]);
        acc[r][1] = fmaf(a[r], b2.y, acc[r][1]);
      }
    }
  };

  constexpr int NS = K / BK;
  gload(0);
  stagewr(0);
  __syncthreads();
  int bb = 0;
#pragma unroll 1
  for (int t = 1; t < NS; ++t) {
    gload(t * BK);
    comp(bb);          // reads buffer bb
    stagewr(bb ^ 1);   // writes buffer bb^1 — disjoint, one barrier suffices
    __syncthreads();
    bb ^= 1;
  }
  comp(bb);

  // ---- epilogue (expressions identical to rounds 1/5) ----
  const float b1v = (MODE == 2) ? 0.f : beta1[k];
  float b2v = 0.f, b3v = 0.f, s2v = 0.f, a1v = 0.f, ap = 0.f;
  if (MODE == 1) {
    b2v = beta2[k - 1];
    b3v = beta3[k - 1];
    s2v = ss2[k - 1];
    a1v = apar1[k - 1];
  }
  if (MODE == 2) ap = apar[k];

#pragma unroll
  for (int r = 0; r < 8; ++r) {
    const size_t off = (size_t)(r0 + r) * BDIM + c0;
    if (MODE == 2) {
      const float2 z2 = *reinterpret_cast<const float2*>(&Zp[off]);
      float2 o;
      o.x = softf(z2.x - acc[r][0], ap);
      o.y = softf(z2.y - acc[r][1], ap);
      *reinterpret_cast<float2*>(&O0[off]) = o;
    } else {
      const float2 e2 = *reinterpret_cast<const float2*>(&Ep[off]);
      const float2 l2 = *reinterpret_cast<const float2*>(&Lp[off]);
      const float2 x2 = *reinterpret_cast<const float2*>(&xg[off]);
      const float ev[2] = {e2.x, e2.y};
      const float lv[2] = {l2.x, l2.y};
      const float xv[2] = {x2.x, x2.y};
      float vo[2], eo[2], lo_[2];
#pragma unroll
      for (int j = 0; j < 2; ++j) {
        const float az = acc[r][j];
        if (MODE == 0) {
          const float t0 = az + ev[j] - xv[j];
          vo[j] = fmaf(b1v, t0, lv[j]);
          eo[j] = ev[j];
          lo_[j] = lv[j];
        } else {
          const float vv = fmaf(b2v, az + ev[j] - xv[j], lv[j]);
          const float en = softf(ev[j] - s2v * vv, a1v);
          const float tn_ = az + en - xv[j];
          const float ln = fmaf(b3v, tn_, lv[j]);
          eo[j] = en;
          lo_[j] = ln;
          vo[j] = fmaf(b1v, tn_, ln);
        }
      }
      float2 t2;
      t2.x = vo[0];
      t2.y = vo[1];
      *reinterpret_cast<float2*>(&O0[off]) = t2;
      t2.x = eo[0];
      t2.y = eo[1];
      *reinterpret_cast<float2*>(&O1[off]) = t2;
      t2.x = lo_[0];
      t2.y = lo_[1];
      *reinterpret_cast<float2*>(&O2[off]) = t2;
    }
  }
}

extern "C" void kernel_launch(void* const* d_in, const int* in_sizes, int n_in,
                              void* d_out, int out_size, void* d_ws,
                              size_t ws_size, hipStream_t stream) {
  (void)in_sizes;
  (void)n_in;
  (void)out_size;
  (void)ws_size;
  const float* x = (const float*)d_in[0];
  const float* A = (const float*)d_in[1];
  const float* W = (const float*)d_in[2];
  const float* Z0 = (const float*)d_in[3];
  const float* E0 = (const float*)d_in[4];
  const float* L0 = (const float*)d_in[5];
  const float* beta1 = (const float*)d_in[6];
  const float* beta2 = (const float*)d_in[7];
  const float* beta3 = (const float*)d_in[8];
  const float* ss2 = (const float*)d_in[9];
  const float* apar = (const float*)d_in[10];
  const float* apar1 = (const float*)d_in[11];

  constexpr size_t DB = (size_t)DDIM * BDIM;
  constexpr size_t MB = (size_t)MDIM * BDIM;
  float* Zall = (float*)d_out;
  float* Eall = Zall + (size_t)NLAYERS * DB;
  float* Lall = Eall + (size_t)NLAYERS * MB;
  float* Var = (float*)d_ws;  // MDIM*BDIM floats = 8 MiB

  const dim3 blk(256);
  const dim3 gA(MDIM / 32, BDIM / 128);  // (16, 32) = 512 blocks
  const dim3 gB(DDIM / 32, BDIM / 128);  // (32, 32) = 1024 blocks

  // layer 0
  gemm_bc<0, DDIM><<<gA, blk, 0, stream>>>(
      A, Z0, x, E0, L0, nullptr, beta1, beta2, beta3, ss2, apar, apar1, 0, Var,
      Eall, Lall);
  gemm_bc<2, MDIM><<<gB, blk, 0, stream>>>(
      W, Var, nullptr, nullptr, nullptr, Z0, beta1, beta2, beta3, ss2, apar,
      apar1, 0, Zall, nullptr, nullptr);
  // layers 1..15
  for (int k = 1; k < NLAYERS; ++k) {
    const float* Zp = Zall + (size_t)(k - 1) * DB;
    gemm_bc<1, DDIM><<<gA, blk, 0, stream>>>(
        A, Zp, x, Eall + (size_t)(k - 1) * MB, Lall + (size_t)(k - 1) * MB,
        nullptr, beta1, beta2, beta3, ss2, apar, apar1, k, Var,
        Eall + (size_t)k * MB, Lall + (size_t)k * MB);
    gemm_bc<2, MDIM><<<gB, blk, 0, stream>>>(
        W + (size_t)k * DDIM * MDIM, Var, nullptr, nullptr, nullptr, Zp, beta1,
        beta2, beta3, ss2, apar, apar1, k, Zall + (size_t)k * DB, nullptr,
        nullptr);
  }
}